// Round 1
// baseline (7740.076 us; speedup 1.0000x reference)
//
#include <hip/hip_runtime.h>

typedef unsigned short u16;
typedef __attribute__((ext_vector_type(8))) short short8;
typedef __attribute__((ext_vector_type(4))) float floatx4;

#define SEQ 1088
#define NROWS 8704   // B * SEQ
#define MFMA16(a, b, c) __builtin_amdgcn_mfma_f32_16x16x32_bf16(a, b, c, 0, 0, 0)

__device__ inline u16 f2bf(float f) {
  unsigned int u = __float_as_uint(f);
  u += 0x7fffu + ((u >> 16) & 1u);   // RNE; inputs are finite
  return (u16)(u >> 16);
}

__device__ inline float gelu_f(float v) {
  return 0.5f * v * (1.0f + erff(v * 0.70710678118654752f));
}

// ---------------------------------------------------------------- embedding
__global__ __launch_bounds__(256)
void embed_kernel(const int* __restrict__ text, const int* __restrict__ image,
                  const float* __restrict__ temb, const float* __restrict__ pemb,
                  float* __restrict__ x) {
  int row = blockIdx.x;              // 0..8703
  int b = row / SEQ, s = row % SEQ;
  int tok = (s < 64) ? text[b * 64 + s] : (image[b * 1024 + (s - 64)] + 16384);
  float4 te = ((const float4*)(temb + (size_t)tok * 1024))[threadIdx.x];
  float4 pe = ((const float4*)(pemb + (size_t)s * 1024))[threadIdx.x];
  float4 o; o.x = te.x + pe.x; o.y = te.y + pe.y; o.z = te.z + pe.z; o.w = te.w + pe.w;
  ((float4*)(x + (size_t)row * 1024))[threadIdx.x] = o;
}

// ---------------------------------------------------------------- layernorm
// mode 0: rows = NROWS, identity mapping. mode 1: rows = 8192, srow = b*SEQ+63+i.
__global__ __launch_bounds__(256)
void ln_kernel(const float* __restrict__ x, u16* __restrict__ hout,
               const float* __restrict__ g, const float* __restrict__ bb, int mode) {
  int row = blockIdx.x;
  int srow = row;
  if (mode) { int b = row >> 10, i = row & 1023; srow = b * SEQ + 63 + i; }
  float4 v = ((const float4*)(x + (size_t)srow * 1024))[threadIdx.x];
  float s = v.x + v.y + v.z + v.w;
  float q = v.x * v.x + v.y * v.y + v.z * v.z + v.w * v.w;
#pragma unroll
  for (int d = 32; d >= 1; d >>= 1) {
    s += __shfl_xor(s, d, 64);
    q += __shfl_xor(q, d, 64);
  }
  __shared__ float red[4][2];
  int wid = threadIdx.x >> 6;
  if ((threadIdx.x & 63) == 0) { red[wid][0] = s; red[wid][1] = q; }
  __syncthreads();
  s = red[0][0] + red[1][0] + red[2][0] + red[3][0];
  q = red[0][1] + red[1][1] + red[2][1] + red[3][1];
  float mu = s * (1.0f / 1024.0f);
  float rs = rsqrtf(q * (1.0f / 1024.0f) - mu * mu + 1e-5f);
  int col = threadIdx.x * 4;
  ushort4 hv;
  hv.x = f2bf((v.x - mu) * rs * g[col + 0] + bb[col + 0]);
  hv.y = f2bf((v.y - mu) * rs * g[col + 1] + bb[col + 1]);
  hv.z = f2bf((v.z - mu) * rs * g[col + 2] + bb[col + 2]);
  hv.w = f2bf((v.w - mu) * rs * g[col + 3] + bb[col + 3]);
  *(ushort4*)(hout + (size_t)row * 1024 + col) = hv;
}

// ------------------------------------------------- weight f32[K][N] -> bf16 [N][K]
__global__ __launch_bounds__(256)
void wtrans_kernel(const float* __restrict__ src, u16* __restrict__ dst, int K, int N) {
  __shared__ float tile[32][33];
  int n0 = blockIdx.x * 32, k0 = blockIdx.y * 32;
  int tx = threadIdx.x & 31, ty = threadIdx.x >> 5;   // 32 x 8
#pragma unroll
  for (int r = 0; r < 4; ++r)
    tile[ty + r * 8][tx] = src[(size_t)(k0 + ty + r * 8) * N + n0 + tx];
  __syncthreads();
#pragma unroll
  for (int r = 0; r < 4; ++r)
    dst[(size_t)(n0 + ty + r * 8) * K + k0 + tx] = f2bf(tile[tx][ty + r * 8]);
}

// ------------------------------------- V: qkv_raw[b,s,2,h,hd] -> vt[b,h,hd,s]
__global__ __launch_bounds__(256)
void vtrans_kernel(const u16* __restrict__ qkv, u16* __restrict__ vt) {
  int st0 = blockIdx.x * 64;
  int bh = blockIdx.y;
  int b = bh >> 4, h = bh & 15;
  __shared__ __align__(16) u16 tile[64][72];
  int tid = threadIdx.x;
#pragma unroll
  for (int it = 0; it < 2; ++it) {
    int c = tid + it * 256;                 // 0..511 chunks of 8
    int s = c >> 3, hd8 = (c & 7) * 8;
    *(uint4*)&tile[s][hd8] =
        *(const uint4*)(qkv + (size_t)(b * SEQ + st0 + s) * 3072 + 2048 + h * 64 + hd8);
  }
  __syncthreads();
#pragma unroll
  for (int it = 0; it < 2; ++it) {
    int c = tid + it * 256;
    int hd = c >> 3, s8 = (c & 7) * 8;
    uint4 o;
    o.x = (unsigned)tile[s8 + 0][hd] | ((unsigned)tile[s8 + 1][hd] << 16);
    o.y = (unsigned)tile[s8 + 2][hd] | ((unsigned)tile[s8 + 3][hd] << 16);
    o.z = (unsigned)tile[s8 + 4][hd] | ((unsigned)tile[s8 + 5][hd] << 16);
    o.w = (unsigned)tile[s8 + 6][hd] | ((unsigned)tile[s8 + 7][hd] << 16);
    *(uint4*)(vt + (size_t)(bh * 64 + hd) * SEQ + st0 + s8) = o;
  }
}

// ---------------------------------------------------------------- GEMM
// C[M,N] = A[M,K](bf16) * Bt[N,K](bf16)^T + bias, epilogues:
// EPI 0: bf16 out; 1: gelu->bf16 out; 2: f32 resid += ; 3: f32 out (no bias)
template <int EPI>
__global__ __launch_bounds__(256)
void gemm_kernel(const u16* __restrict__ A, const u16* __restrict__ Bt,
                 const float* __restrict__ bias, u16* __restrict__ outb,
                 float* __restrict__ outf, int M, int N, int K) {
  const int tid = threadIdx.x;
  const int l = tid & 63, w = tid >> 6;
  const int wm = (w & 1) * 64, wn = (w >> 1) * 64;
  const int lm = l & 15, lk8 = (l >> 4) * 8, r4 = (l >> 4) * 4;
  const int m0 = blockIdx.y * 128, n0 = blockIdx.x * 128;
  __shared__ __align__(16) u16 As[128][72];
  __shared__ __align__(16) u16 Bs[128][72];
  floatx4 acc[4][4];
#pragma unroll
  for (int mi = 0; mi < 4; ++mi)
#pragma unroll
    for (int ni = 0; ni < 4; ++ni)
#pragma unroll
      for (int i = 0; i < 4; ++i) acc[mi][ni][i] = 0.0f;

  for (int kt = 0; kt < K; kt += 64) {
    __syncthreads();
#pragma unroll
    for (int it = 0; it < 4; ++it) {
      int c = tid + it * 256;            // 0..1023 chunks of 8 elems
      int row = c >> 3, col8 = (c & 7) * 8;
      *(uint4*)&As[row][col8] = *(const uint4*)(A + (size_t)(m0 + row) * K + kt + col8);
      *(uint4*)&Bs[row][col8] = *(const uint4*)(Bt + (size_t)(n0 + row) * K + kt + col8);
    }
    __syncthreads();
#pragma unroll
    for (int s = 0; s < 2; ++s) {
      short8 af[4], bf[4];
#pragma unroll
      for (int mi = 0; mi < 4; ++mi) af[mi] = *(const short8*)&As[wm + mi * 16 + lm][s * 32 + lk8];
#pragma unroll
      for (int ni = 0; ni < 4; ++ni) bf[ni] = *(const short8*)&Bs[wn + ni * 16 + lm][s * 32 + lk8];
#pragma unroll
      for (int mi = 0; mi < 4; ++mi)
#pragma unroll
        for (int ni = 0; ni < 4; ++ni)
          acc[mi][ni] = MFMA16(af[mi], bf[ni], acc[mi][ni]);
    }
  }
#pragma unroll
  for (int mi = 0; mi < 4; ++mi)
#pragma unroll
    for (int ni = 0; ni < 4; ++ni) {
      int row = m0 + wm + mi * 16 + r4;
      int col = n0 + wn + ni * 16 + lm;
      float bv = (EPI == 3) ? 0.0f : bias[col];
#pragma unroll
      for (int i = 0; i < 4; ++i) {
        float v = acc[mi][ni][i] + bv;
        size_t idx = (size_t)(row + i) * N + col;
        if (EPI == 0) outb[idx] = f2bf(v);
        else if (EPI == 1) outb[idx] = f2bf(gelu_f(v));
        else if (EPI == 2) outf[idx] += v;
        else outf[idx] = v;
      }
    }
}

// ---------------------------------------------------------------- attention
// One WG per (q-tile of 64 rows, b*h). 4 waves; wave w owns q rows [qb+16w, +16).
__global__ __launch_bounds__(256)
void attn_kernel(const u16* __restrict__ qkv, const u16* __restrict__ vt,
                 u16* __restrict__ o) {
  const int qt = blockIdx.x;
  const int bh = blockIdx.y;
  const int b = bh >> 4, h = bh & 15;
  const int tid = threadIdx.x;
  const int l = tid & 63, w = tid >> 6;
  const int lm = l & 15, lk8 = (l >> 4) * 8, r4 = (l >> 4) * 4;
  const int qb = qt * 64;

  __shared__ __align__(16) u16 Ks[64][72];
  __shared__ __align__(16) u16 Vs[64][72];
  __shared__ __align__(16) u16 Ps[4][16][72];

  const int qrow = qb + w * 16 + lm;
  const u16* qp = qkv + (size_t)(b * SEQ + qrow) * 3072 + h * 64;
  short8 aq0 = *(const short8*)(qp + lk8);
  short8 aq1 = *(const short8*)(qp + 32 + lk8);

  floatx4 acc[4];
  float mrow[4], lrow[4];
#pragma unroll
  for (int i = 0; i < 4; ++i) { mrow[i] = -1e30f; lrow[i] = 0.0f; }
#pragma unroll
  for (int di = 0; di < 4; ++di)
#pragma unroll
    for (int i = 0; i < 4; ++i) acc[di][i] = 0.0f;

  for (int kt = 0; kt <= qt; ++kt) {
    const int kb = kt * 64;
    __syncthreads();
#pragma unroll
    for (int it = 0; it < 2; ++it) {
      int c = tid + it * 256;
      int row = c >> 3, col8 = (c & 7) * 8;
      *(uint4*)&Ks[row][col8] =
          *(const uint4*)(qkv + (size_t)(b * SEQ + kb + row) * 3072 + 1024 + h * 64 + col8);
      *(uint4*)&Vs[row][col8] = *(const uint4*)(vt + (size_t)(bh * 64 + row) * SEQ + kb + col8);
    }
    __syncthreads();

    float st[4][4];
#pragma unroll
    for (int ni = 0; ni < 4; ++ni) {
      short8 bk0 = *(const short8*)&Ks[ni * 16 + lm][lk8];
      short8 bk1 = *(const short8*)&Ks[ni * 16 + lm][32 + lk8];
      floatx4 z; z[0] = 0.0f; z[1] = 0.0f; z[2] = 0.0f; z[3] = 0.0f;
      z = MFMA16(aq0, bk0, z);
      z = MFMA16(aq1, bk1, z);
#pragma unroll
      for (int i = 0; i < 4; ++i) {
        float s = z[i] * 0.125f;                    // 1/sqrt(64)
        if (kt == qt && (kb + ni * 16 + lm) > (qb + w * 16 + r4 + i)) s = -1e30f;
        st[ni][i] = s;
      }
    }
    float mx[4], ls[4], al[4];
#pragma unroll
    for (int i = 0; i < 4; ++i)
      mx[i] = fmaxf(fmaxf(st[0][i], st[1][i]), fmaxf(st[2][i], st[3][i]));
#pragma unroll
    for (int d = 1; d < 16; d <<= 1)
#pragma unroll
      for (int i = 0; i < 4; ++i) mx[i] = fmaxf(mx[i], __shfl_xor(mx[i], d, 64));
#pragma unroll
    for (int i = 0; i < 4; ++i) {
      float mn = fmaxf(mrow[i], mx[i]);
      al[i] = __expf(mrow[i] - mn);
      mrow[i] = mn;
      ls[i] = 0.0f;
    }
#pragma unroll
    for (int ni = 0; ni < 4; ++ni)
#pragma unroll
      for (int i = 0; i < 4; ++i) {
        float p = __expf(st[ni][i] - mrow[i]);
        Ps[w][r4 + i][ni * 16 + lm] = f2bf(p);
        ls[i] += p;
      }
#pragma unroll
    for (int d = 1; d < 16; d <<= 1)
#pragma unroll
      for (int i = 0; i < 4; ++i) ls[i] += __shfl_xor(ls[i], d, 64);
#pragma unroll
    for (int i = 0; i < 4; ++i) lrow[i] = lrow[i] * al[i] + ls[i];
#pragma unroll
    for (int di = 0; di < 4; ++di)
#pragma unroll
      for (int i = 0; i < 4; ++i) acc[di][i] *= al[i];

    // P (C-layout, just written) -> A-layout read; same-wave LDS dependency,
    // compiler inserts the lgkmcnt wait.
    short8 ap0 = *(const short8*)&Ps[w][lm][lk8];
    short8 ap1 = *(const short8*)&Ps[w][lm][32 + lk8];
#pragma unroll
    for (int di = 0; di < 4; ++di) {
      short8 bv0 = *(const short8*)&Vs[di * 16 + lm][lk8];
      short8 bv1 = *(const short8*)&Vs[di * 16 + lm][32 + lk8];
      acc[di] = MFMA16(ap0, bv0, acc[di]);
      acc[di] = MFMA16(ap1, bv1, acc[di]);
    }
  }
#pragma unroll
  for (int di = 0; di < 4; ++di)
#pragma unroll
    for (int i = 0; i < 4; ++i) {
      int s = qb + w * 16 + r4 + i;
      o[(size_t)(b * SEQ + s) * 1024 + h * 64 + di * 16 + lm] = f2bf(acc[di][i] / lrow[i]);
    }
}

// ---------------------------------------------------------------- host
extern "C" void kernel_launch(void* const* d_in, const int* in_sizes, int n_in,
                              void* d_out, int out_size, void* d_ws, size_t ws_size,
                              hipStream_t stream) {
  const int*   text      = (const int*)d_in[0];
  const int*   image     = (const int*)d_in[1];
  const float* token_emb = (const float*)d_in[2];
  const float* pos_emb   = (const float*)d_in[3];
  const float* qkv_w     = (const float*)d_in[4];
  const float* qkv_b     = (const float*)d_in[5];
  const float* out_w     = (const float*)d_in[6];
  const float* out_b     = (const float*)d_in[7];
  const float* ln1_g     = (const float*)d_in[8];
  const float* ln1_b     = (const float*)d_in[9];
  const float* ln2_g     = (const float*)d_in[10];
  const float* ln2_b     = (const float*)d_in[11];
  const float* ff1_w     = (const float*)d_in[12];
  const float* ff1_b     = (const float*)d_in[13];
  const float* ff2_w     = (const float*)d_in[14];
  const float* ff2_b     = (const float*)d_in[15];
  const float* lnf_g     = (const float*)d_in[16];
  const float* lnf_b     = (const float*)d_in[17];
  const float* head_w    = (const float*)d_in[18];
  float* out = (float*)d_out;

  char* p = (char*)d_ws;
  auto take = [&](size_t nbytes) -> char* {
    char* r = p;
    p += (nbytes + 255) & ~(size_t)255;
    return r;
  };
  float* x      = (float*)take((size_t)NROWS * 1024 * 4);
  u16* hbuf     = (u16*)take((size_t)NROWS * 1024 * 2);
  u16* qkvraw   = (u16*)take((size_t)NROWS * 3072 * 2);
  u16* vtb      = (u16*)take((size_t)128 * 64 * SEQ * 2);
  u16* obuf     = (u16*)take((size_t)NROWS * 1024 * 2);
  u16* ffh      = (u16*)take((size_t)NROWS * 4096 * 2);
  u16* hsel     = (u16*)take((size_t)8192 * 1024 * 2);
  u16* wq_t     = (u16*)take((size_t)3072 * 1024 * 2);
  u16* wo_t     = (u16*)take((size_t)1024 * 1024 * 2);
  u16* wf1_t    = (u16*)take((size_t)4096 * 1024 * 2);
  u16* wf2_t    = (u16*)take((size_t)4096 * 1024 * 2);
  u16* whead_t  = (u16*)take((size_t)8192 * 1024 * 2);

  dim3 blk(256);

  wtrans_kernel<<<dim3(8192 / 32, 1024 / 32), blk, 0, stream>>>(head_w, whead_t, 1024, 8192);
  embed_kernel<<<dim3(NROWS), blk, 0, stream>>>(text, image, token_emb, pos_emb, x);

  for (int L = 0; L < 12; ++L) {
    ln_kernel<<<dim3(NROWS), blk, 0, stream>>>(x, hbuf, ln1_g + L * 1024, ln1_b + L * 1024, 0);
    wtrans_kernel<<<dim3(3072 / 32, 1024 / 32), blk, 0, stream>>>(
        qkv_w + (size_t)L * 1024 * 3072, wq_t, 1024, 3072);
    gemm_kernel<0><<<dim3(3072 / 128, NROWS / 128), blk, 0, stream>>>(
        hbuf, wq_t, qkv_b + L * 3072, qkvraw, nullptr, NROWS, 3072, 1024);
    vtrans_kernel<<<dim3(17, 128), blk, 0, stream>>>(qkvraw, vtb);
    attn_kernel<<<dim3(17, 128), blk, 0, stream>>>(qkvraw, vtb, obuf);
    wtrans_kernel<<<dim3(1024 / 32, 1024 / 32), blk, 0, stream>>>(
        out_w + (size_t)L * 1024 * 1024, wo_t, 1024, 1024);
    gemm_kernel<2><<<dim3(1024 / 128, NROWS / 128), blk, 0, stream>>>(
        obuf, wo_t, out_b + L * 1024, nullptr, x, NROWS, 1024, 1024);
    ln_kernel<<<dim3(NROWS), blk, 0, stream>>>(x, hbuf, ln2_g + L * 1024, ln2_b + L * 1024, 0);
    wtrans_kernel<<<dim3(4096 / 32, 1024 / 32), blk, 0, stream>>>(
        ff1_w + (size_t)L * 1024 * 4096, wf1_t, 1024, 4096);
    gemm_kernel<1><<<dim3(4096 / 128, NROWS / 128), blk, 0, stream>>>(
        hbuf, wf1_t, ff1_b + L * 4096, ffh, nullptr, NROWS, 4096, 1024);
    wtrans_kernel<<<dim3(1024 / 32, 4096 / 32), blk, 0, stream>>>(
        ff2_w + (size_t)L * 4096 * 1024, wf2_t, 4096, 1024);
    gemm_kernel<2><<<dim3(1024 / 128, NROWS / 128), blk, 0, stream>>>(
        ffh, wf2_t, ff2_b + L * 1024, nullptr, x, NROWS, 1024, 4096);
  }

  ln_kernel<<<dim3(8192), blk, 0, stream>>>(x, hsel, lnf_g, lnf_b, 1);
  gemm_kernel<3><<<dim3(8192 / 128, 8192 / 128), blk, 0, stream>>>(
      hsel, whead_t, nullptr, nullptr, out, 8192, 8192, 1024);
}